// Round 2
// baseline (920.475 us; speedup 1.0000x reference)
//
#include <hip/hip_runtime.h>
#include <cstdint>
#include <cstddef>

// ---------------------------------------------------------------------------
// HeliosAttention: hs->fused QKV proj(bf16 out + sumsq partials) -> in-place
// RMSNorm+RoPE -> 2-segment SDPA -> out proj.  B=2 S=3072 DIM=2048 H=16 HD=128
// R6: attention rewritten for LDS-bandwidth (the measured wall):
//   - 64q per wave (f=4), 256q per block: K/V LDS reads amortized 2x
//   - K/V staged via global_load_lds, linear LDS + XOR slot swizzle both sides
//   - 3-barrier drain-early pipeline (K hidden under PV, V under QK)
//   - Ps ping-pong 32-key half buffer (LDS 52KB -> 2 blocks/CU)
// GEMMs: 256x256 8-phase counted-vmcnt template (R5, unchanged).
// ---------------------------------------------------------------------------

typedef __bf16 bf16_t;
typedef __attribute__((ext_vector_type(8))) __bf16 bf16x8;
typedef __attribute__((ext_vector_type(4))) __bf16 bf16x4;
typedef __attribute__((ext_vector_type(4))) float f32x4;
typedef __attribute__((ext_vector_type(4))) unsigned int u32x4;

#define NB   2
#define NS   3072
#define ND   2048
#define NH   16
#define NHD  128
#define NTOK (NB * NS)      // 6144
#define NHIST 1024
#define N3   (3 * ND)       // 6144 fused QKV row width

__device__ __forceinline__ f32x4 mfma16(bf16x8 a, bf16x8 b, f32x4 c) {
    return __builtin_amdgcn_mfma_f32_16x16x32_bf16(a, b, c, 0, 0, 0);
}

// async global->LDS, 16B per lane. LDS dst MUST be wave-uniform base + lane*16.
__device__ __forceinline__ void async16(const bf16_t* gsrc, bf16_t* ldst) {
    __builtin_amdgcn_global_load_lds(
        (const __attribute__((address_space(1))) void*)gsrc,
        (__attribute__((address_space(3))) void*)ldst,
        16, 0, 0);
}

// ---------------- fp32 -> bf16 elementwise cast ----------------
__global__ __launch_bounds__(256) void cast_bf16_kernel(const float* __restrict__ src,
                                                        bf16_t* __restrict__ dst, int n4) {
    int i = blockIdx.x * 256 + threadIdx.x;
    if (i >= n4) return;
    f32x4 v = ((const f32x4*)src)[i];
    bf16x4 o;
    o[0] = (bf16_t)v[0]; o[1] = (bf16_t)v[1];
    o[2] = (bf16_t)v[2]; o[3] = (bf16_t)v[3];
    ((bf16x4*)dst)[i] = o;
}

// ---------------- concat bq|bk|bv -> 6144 floats ----------------
__global__ __launch_bounds__(256) void bias_concat_kernel(const float* __restrict__ bq,
                                                          const float* __restrict__ bk,
                                                          const float* __restrict__ bv,
                                                          float* __restrict__ dst) {
    int i = blockIdx.x * 256 + threadIdx.x;
    if (i >= N3) return;
    dst[i] = (i < ND) ? bq[i] : (i < 2 * ND ? bk[i - ND] : bv[i - 2 * ND]);
}

// ---------------------------------------------------------------------------
// 256x256 tile GEMM, C = A * B^T + bias (R5 8-phase counted-vmcnt template).
// MODE 1: bf16 C + fp32 sumsq partials (QKV).  MODE 0: f32 C (O-proj).
// ---------------------------------------------------------------------------
template<int MODE>
__global__ __launch_bounds__(512, 2) void gemm256(const bf16_t* __restrict__ A,
                                                  const bf16_t* __restrict__ Bm,
                                                  const float* __restrict__ bias,
                                                  void* __restrict__ Cout,
                                                  float* __restrict__ Psum,
                                                  int N, int K) {
    __shared__ __align__(16) char smem[131072];
    const int tid  = threadIdx.x;
    const int wid  = tid >> 6, lane = tid & 63;
    const int g    = lane >> 4, c = lane & 15;
    const int wr   = wid >> 2, wc = wid & 3;

    const int gx = gridDim.x, gy = gridDim.y;
    const int nwg = gx * gy;
    const int bid = blockIdx.y * gx + blockIdx.x;
    const int cpx = nwg >> 3;
    const int swz = (bid & 7) * cpx + (bid >> 3);
    const int bx = swz / gy, by = swz % gy;
    const int m0 = by * 256, n0 = bx * 256;

    const int r0 = tid >> 2, sq = tid & 3;
    const int sd = sq ^ ((r0 >> 1) & 3);
    const bf16_t* At = A  + (size_t)(m0 + r0) * K + sd * 8;
    const bf16_t* Bt = Bm + (size_t)(n0 + r0) * K + sd * 8;
    const size_t rs128 = (size_t)128 * K;

    const int axor = ((c >> 1) & 3) << 4;
    const int gb   = (g << 4) ^ axor;
    const int aRow = (wr * 128 + c) * 64 + gb;
    const int bRow = 32768 + (wc * 64 + c) * 64 + gb;

    f32x4 acc[8][4];
#pragma unroll
    for (int i = 0; i < 8; i++)
#pragma unroll
        for (int j = 0; j < 4; j++) acc[i][j] = (f32x4){0.f, 0.f, 0.f, 0.f};

    auto stA = [&](int kt, int kh, int db) {
        const bf16_t* s = At + (size_t)kt * 64 + kh * 32;
        char* d = smem + db * 65536 + kh * 16384 + tid * 16;
        async16(s, (bf16_t*)d);
        async16(s + rs128, (bf16_t*)(d + 8192));
    };
    auto stB = [&](int kt, int kh, int db) {
        const bf16_t* s = Bt + (size_t)kt * 64 + kh * 32;
        char* d = smem + db * 65536 + 32768 + kh * 16384 + tid * 16;
        async16(s, (bf16_t*)d);
        async16(s + rs128, (bf16_t*)(d + 8192));
    };

    const int nkt = K >> 6;
    stA(0, 0, 0); stB(0, 0, 0); stA(0, 1, 0); stB(0, 1, 0);
    stA(1, 0, 1); stB(1, 0, 1);
    asm volatile("s_waitcnt vmcnt(4)" ::: "memory");
    __builtin_amdgcn_s_barrier();
    asm volatile("" ::: "memory");

    auto tile = [&](int t, int db) {
        const int kt1 = (t + 1 < nkt) ? t + 1 : 0;
        const int kt2 = (t + 2 < nkt) ? t + 2 : 0;
        const char* base = smem + db * 65536;
        bf16x8 Bf[4], Af[4];
#pragma unroll
        for (int ph = 0; ph < 4; ph++) {
            const int ks = ph >> 1, mh = ph & 1;
            if (mh == 0) {
#pragma unroll
                for (int ni = 0; ni < 4; ni++)
                    Bf[ni] = *(const bf16x8*)(base + ks * 16384 + ni * 1024 + bRow);
            }
#pragma unroll
            for (int r4 = 0; r4 < 4; r4++)
                Af[r4] = *(const bf16x8*)(base + ks * 16384 + (mh * 4 + r4) * 1024 + aRow);
            if (ph == 0)      stA(kt1, 1, db ^ 1);
            else if (ph == 1) stB(kt1, 1, db ^ 1);
            else if (ph == 2) stA(kt2, 0, db);
            else {            stB(kt2, 0, db);
                              asm volatile("s_waitcnt vmcnt(4)" ::: "memory"); }
            asm volatile("" ::: "memory");
            __builtin_amdgcn_s_barrier();
            asm volatile("" ::: "memory");
            __builtin_amdgcn_s_setprio(1);
#pragma unroll
            for (int r4 = 0; r4 < 4; r4++)
#pragma unroll
                for (int ni = 0; ni < 4; ni++)
                    acc[mh * 4 + r4][ni] = mfma16(Af[r4], Bf[ni], acc[mh * 4 + r4][ni]);
            __builtin_amdgcn_s_setprio(0);
            asm volatile("" ::: "memory");
            __builtin_amdgcn_s_barrier();
            asm volatile("" ::: "memory");
        }
    };

#pragma unroll 1
    for (int t = 0; t < nkt; t += 2) { tile(t, 0); tile(t + 1, 1); }

    asm volatile("s_waitcnt vmcnt(0)" ::: "memory");

    float bi[4];
#pragma unroll
    for (int ni = 0; ni < 4; ni++) bi[ni] = bias[n0 + wc * 64 + ni * 16 + c];
    if (MODE == 1) {
        bf16_t* C = (bf16_t*)Cout;
        const int grp = (n0 >> 6) + wc;
#pragma unroll
        for (int mi = 0; mi < 8; mi++) {
#pragma unroll
            for (int i = 0; i < 4; i++) {
                int m = m0 + wr * 128 + mi * 16 + g * 4 + i;
                bf16_t* crow = C + (size_t)m * N + n0 + wc * 64 + c;
                float s = 0.f;
#pragma unroll
                for (int ni = 0; ni < 4; ni++) {
                    float v = acc[mi][ni][i] + bi[ni];
                    crow[ni * 16] = (bf16_t)v;
                    s += v * v;
                }
#pragma unroll
                for (int msk = 1; msk < 16; msk <<= 1) s += __shfl_xor(s, msk);
                if (c == 0) Psum[(size_t)m * 96 + grp] = s;
            }
        }
    } else {
        float* C = (float*)Cout;
#pragma unroll
        for (int mi = 0; mi < 8; mi++) {
#pragma unroll
            for (int i = 0; i < 4; i++) {
                int m = m0 + wr * 128 + mi * 16 + g * 4 + i;
                float* crow = C + (size_t)m * N + n0 + wc * 64 + c;
#pragma unroll
                for (int ni = 0; ni < 4; ni++) crow[ni * 16] = acc[mi][ni][i] + bi[ni];
            }
        }
    }
}

// ---------------- in-place RMSNorm + RoPE on bf16 QKV rows ----------------
__global__ __launch_bounds__(256) void rmsrope2_kernel(bf16_t* __restrict__ QKV,
                                                       const float* __restrict__ Psum,
                                                       const float* __restrict__ gq,
                                                       const float* __restrict__ gk,
                                                       const float* __restrict__ rot,
                                                       float qscale) {
    const int t = blockIdx.x;
    const int s = t % NS;
    const int tid = threadIdx.x;
    __shared__ float sh[2];
    float p = 0.f;
    if (tid < 64) p = Psum[(size_t)t * 96 + tid];
#pragma unroll
    for (int msk = 1; msk < 32; msk <<= 1) p += __shfl_xor(p, msk);
    if (tid == 0) sh[0] = p;
    if (tid == 32) sh[1] = p;
    __syncthreads();
    const float sclQ = rsqrtf(sh[0] * (1.f / (float)ND) + 1e-6f);
    const float sclK = rsqrtf(sh[1] * (1.f / (float)ND) + 1e-6f);

    const int col = tid * 8, hd = col & (NHD - 1);
    const float* rr = rot + (size_t)s * (2 * NHD);
    float cc[4], sn[4];
#pragma unroll
    for (int u = 0; u < 4; u++) {
        cc[u] = rr[hd + 2 * u];
        sn[u] = rr[NHD + hd + 2 * u + 1];
    }
    bf16_t* row = QKV + (size_t)t * N3;

    bf16x8 xq = *(bf16x8*)(row + col);
    bf16x8 xk = *(bf16x8*)(row + ND + col);
    bf16x8 oq, ok;
#pragma unroll
    for (int u = 0; u < 4; u++) {
        float e  = (float)xq[2 * u]     * sclQ * gq[col + 2 * u];
        float od = (float)xq[2 * u + 1] * sclQ * gq[col + 2 * u + 1];
        oq[2 * u]     = (bf16_t)((e * cc[u] - od * sn[u]) * qscale);
        oq[2 * u + 1] = (bf16_t)((e * sn[u] + od * cc[u]) * qscale);
        float ek  = (float)xk[2 * u]     * sclK * gk[col + 2 * u];
        float odk = (float)xk[2 * u + 1] * sclK * gk[col + 2 * u + 1];
        ok[2 * u]     = (bf16_t)(ek * cc[u] - odk * sn[u]);
        ok[2 * u + 1] = (bf16_t)(ek * sn[u] + odk * cc[u]);
    }
    *(bf16x8*)(row + col) = oq;
    *(bf16x8*)(row + ND + col) = ok;
}

// ---------------- V transpose: QKV bf16 V-cols -> [bh][d][s] ----------------
__global__ __launch_bounds__(256) void vtrans_kernel(const bf16_t* __restrict__ QKV,
                                                     bf16_t* __restrict__ VTg) {
    __shared__ bf16_t T[128 * 65];
    const int tid = threadIdx.x;
    const int st = blockIdx.x;
    const int bh = blockIdx.y;
    const int b = bh >> 4, h = bh & 15;
    const int ds = tid >> 4, ssx = tid & 15;
#pragma unroll
    for (int i = 0; i < 4; i++) {
        int sl = ssx + i * 16;
        const bf16_t* xr = QKV + (size_t)(b * NS + st * 64 + sl) * N3 + 2 * ND + h * NHD;
        bf16x8 v = *(const bf16x8*)(xr + ds * 8);
#pragma unroll
        for (int u = 0; u < 8; u++) T[(ds * 8 + u) * 65 + sl] = v[u];
    }
    __syncthreads();
#pragma unroll
    for (int q = 0; q < 4; q++) {
        int chunk = q * 256 + tid;
        int d = chunk >> 3, sc8 = chunk & 7;
        bf16x8 o;
#pragma unroll
        for (int u = 0; u < 8; u++) o[u] = T[d * 65 + sc8 * 8 + u];
        *(bf16x8*)(VTg + ((size_t)bh * NHD + d) * NS + st * 64 + sc8 * 8) = o;
    }
}

// ---------------- flash attention: 64q/wave, async-staged K/V ---------------
// Per block: 256q (4 waves x 64q, f=0..3 subtiles of 16).  K tile [64k][128d]
// and V^T tile [128d][64k] staged via global_load_lds into LINEAR LDS with
// XOR slot swizzle applied on the global SOURCE; ds_reads apply the same XOR
// -> every b128 read is 2-lane/bank (free).  3 barriers/iter; all DMAs are
// drained ~500+cyc after issue just before a barrier (latency hidden under
// compute).  P goes through a per-wave 32-key ping-pong LDS buffer.
__global__ __launch_bounds__(256, 2) void attn_kernel(const bf16_t* __restrict__ QKV,
                                                      const bf16_t* __restrict__ Vg,
                                                      bf16_t* __restrict__ Og,
                                                      float* __restrict__ PartA,
                                                      float* __restrict__ PartB,
                                                      float* __restrict__ PartL) {
    __shared__ bf16_t Ks[64 * 128];        // [key][d] linear + slot swizzle (16KB)
    __shared__ bf16_t Vs[128 * 64];        // [d][key] linear + slot swizzle (16KB)
    __shared__ bf16_t Ps[4][64 * 40];      // per-wave P [64q][32k ping-pong] (20KB)
    const int tid = threadIdx.x;
    const int w = tid >> 6, lane = tid & 63;
    const int g = lane >> 4, c = lane & 15;
    const int x = blockIdx.x, bh = blockIdx.y;
    const int b = bh >> 4, h = bh & 15;
    const float FM = 18.0f;

    int qb, k0, niter, tile;
    bool direct;
    if (x < 4) { qb = x; k0 = 0; niter = 16; direct = true; tile = 0; }
    else {
        int t = x - 4;
        qb = 4 + (t >> 1);
        int ch = t & 1;
        k0 = ch * 1536; niter = 24; direct = false;
        tile = (bh * 8 + (qb - 4)) * 2 + ch;      // 0..511
    }
    const int q0 = qb * 256 + w * 64;

    // Q fragments: 4 q-subtiles x 4 d-chunks, registers for the whole kernel
    bf16x8 qf[4][4];
#pragma unroll
    for (int f = 0; f < 4; f++) {
        const bf16_t* qrow = QKV + (size_t)(b * NS + q0 + f * 16 + c) * N3 + h * NHD;
#pragma unroll
        for (int d = 0; d < 4; d++) qf[f][d] = *(const bf16x8*)(qrow + d * 32 + g * 8);
    }

    f32x4 o[4][8];
#pragma unroll
    for (int f = 0; f < 4; f++)
#pragma unroll
        for (int nt = 0; nt < 8; nt++) o[f][nt] = (f32x4){0.f, 0.f, 0.f, 0.f};
    float l[4] = {0.f, 0.f, 0.f, 0.f};

    // staging offsets: 4 K-DMA + 4 V-DMA per iter; source is inverse-swizzled
    int koff[4], voff[4];
#pragma unroll
    for (int j = 0; j < 4; j++) {
        int r = 16 * j + 4 * w + (lane >> 4);          // K row within tile
        koff[j] = r * N3 + (((lane & 15) ^ (r & 7)) * 8);
        int d = 32 * j + 8 * w + (lane >> 3);          // V d-row
        voff[j] = d * NS + (((lane & 7) ^ (d & 7)) * 8);
    }
    const bf16_t* kg = QKV + (size_t)(b * NS) * N3 + ND + h * NHD;
    const bf16_t* vg = Vg + (size_t)bh * NHD * NS;

    // prologue: stage tile 0, drain, sync
#pragma unroll
    for (int j = 0; j < 4; j++) {
        async16(kg + (size_t)k0 * N3 + koff[j], &Ks[j * 2048 + tid * 8]);
        async16(vg + (size_t)k0 + voff[j],      &Vs[j * 2048 + tid * 8]);
    }
    asm volatile("s_waitcnt vmcnt(0)" ::: "memory");
    __syncthreads();

    bf16_t* pw = &Ps[w][0];
    const int c7 = c & 7;

    for (int it = 0; it < niter; it++) {
        const int kbn = k0 + (it + 1) * 64;
        const bool more = (it + 1 < niter);

        // ---- QK kt=0,1 (keys 0..31), P -> cols 0..31 ----
#pragma unroll
        for (int kt = 0; kt < 2; kt++) {
            f32x4 sv[4];
#pragma unroll
            for (int f = 0; f < 4; f++) sv[f] = (f32x4){0.f, 0.f, 0.f, 0.f};
#pragma unroll
            for (int dd = 0; dd < 4; dd++) {
                bf16x8 kf = *(const bf16x8*)&Ks[(kt * 16 + c) * 128 + (((dd * 4 + g) ^ c7) * 8)];
#pragma unroll
                for (int f = 0; f < 4; f++) sv[f] = mfma16(kf, qf[f][dd], sv[f]);
            }
#pragma unroll
            for (int f = 0; f < 4; f++) {
                bf16x4 pk;
#pragma unroll
                for (int i = 0; i < 4; i++) {
                    float pv = exp2f(sv[f][i] - FM);
                    l[f] += pv;
                    pk[i] = (bf16_t)pv;
                }
                *(bf16x4*)&pw[(f * 16 + c) * 40 + (kt & 1) * 16 + g * 4] = pk;
            }
        }
        // drain V(t) DMA (issued end of prev iter), then block-wide ready
        asm volatile("s_waitcnt vmcnt(0)" ::: "memory");
        __syncthreads();
        // ---- PV half 0 (keys 0..31) ----
        {
            bf16x8 pf[4];
#pragma unroll
            for (int f = 0; f < 4; f++)
                pf[f] = *(const bf16x8*)&pw[(f * 16 + c) * 40 + g * 8];
            __builtin_amdgcn_s_setprio(1);
#pragma unroll
            for (int nt = 0; nt < 8; nt++) {
                bf16x8 vf = *(const bf16x8*)&Vs[(nt * 16 + c) * 64 + ((g ^ c7) * 8)];
#pragma unroll
                for (int f = 0; f < 4; f++) o[f][nt] = mfma16(vf, pf[f], o[f][nt]);
            }
            __builtin_amdgcn_s_setprio(0);
        }
        // ---- QK kt=2,3 (keys 32..63), P -> cols 0..31 (ping-pong reuse) ----
#pragma unroll
        for (int kt = 2; kt < 4; kt++) {
            f32x4 sv[4];
#pragma unroll
            for (int f = 0; f < 4; f++) sv[f] = (f32x4){0.f, 0.f, 0.f, 0.f};
#pragma unroll
            for (int dd = 0; dd < 4; dd++) {
                bf16x8 kf = *(const bf16x8*)&Ks[(kt * 16 + c) * 128 + (((dd * 4 + g) ^ c7) * 8)];
#pragma unroll
                for (int f = 0; f < 4; f++) sv[f] = mfma16(kf, qf[f][dd], sv[f]);
            }
#pragma unroll
            for (int f = 0; f < 4; f++) {
                bf16x4 pk;
#pragma unroll
                for (int i = 0; i < 4; i++) {
                    float pv = exp2f(sv[f][i] - FM);
                    l[f] += pv;
                    pk[i] = (bf16_t)pv;
                }
                *(bf16x4*)&pw[(f * 16 + c) * 40 + (kt & 1) * 16 + g * 4] = pk;
            }
        }
        __syncthreads();           // all waves done reading Ks(t)
        if (more) {                // K(t+1) flies under PV half 1 + barrier
#pragma unroll
            for (int j = 0; j < 4; j++)
                async16(kg + (size_t)kbn * N3 + koff[j], &Ks[j * 2048 + tid * 8]);
        }
        // ---- PV half 1 (keys 32..63) ----
        {
            bf16x8 pf[4];
#pragma unroll
            for (int f = 0; f < 4; f++)
                pf[f] = *(const bf16x8*)&pw[(f * 16 + c) * 40 + g * 8];
            __builtin_amdgcn_s_setprio(1);
#pragma unroll
            for (int nt = 0; nt < 8; nt++) {
                bf16x8 vf = *(const bf16x8*)&Vs[(nt * 16 + c) * 64 + (((4 + g) ^ c7) * 8)];
#pragma unroll
                for (int f = 0; f < 4; f++) o[f][nt] = mfma16(vf, pf[f], o[f][nt]);
            }
            __builtin_amdgcn_s_setprio(0);
        }
        asm volatile("s_waitcnt vmcnt(0)" ::: "memory");   // drain K(t+1)
        __syncthreads();           // all waves done reading Vs(t); Ks(t+1) ready
        if (more) {                // V(t+1) flies under next iter's QK
#pragma unroll
            for (int j = 0; j < 4; j++)
                async16(vg + (size_t)kbn + voff[j], &Vs[j * 2048 + tid * 8]);
        }
    }

    if (direct) {
#pragma unroll
        for (int f = 0; f < 4; f++) {
            float lt = l[f];
            lt += __shfl_xor(lt, 16);
            lt += __shfl_xor(lt, 32);
            float inv = 1.0f / lt;
            bf16_t* orow = Og + (((size_t)b * NS + q0 + f * 16 + c) * NH + h) * NHD;
#pragma unroll
            for (int nt = 0; nt < 8; nt++) {
                bf16x4 ov;
#pragma unroll
                for (int i = 0; i < 4; i++) ov[i] = (bf16_t)(o[f][nt][i] * inv);
                *(bf16x4*)(orow + nt * 16 + g * 4) = ov;
            }
        }
    } else {
        float* pt = (tile < 384) ? (PartA + (size_t)tile * 32768)
                                 : (PartB + (size_t)(tile - 384) * 32768);
#pragma unroll
        for (int f = 0; f < 4; f++) {
            float lt = l[f];
            lt += __shfl_xor(lt, 16);
            lt += __shfl_xor(lt, 32);
            if (g == 0) PartL[(size_t)tile * 256 + w * 64 + f * 16 + c] = lt;
            float* prow = pt + (w * 64 + f * 16 + c) * 128;
#pragma unroll
            for (int nt = 0; nt < 8; nt++)
                *(f32x4*)(prow + nt * 16 + g * 4) = o[f][nt];
        }
    }
}

// ---------------- combine: sum 2 chunk partials, normalize, write bf16 Ob ----
__global__ __launch_bounds__(256) void combine_kernel(const float* __restrict__ PartA,
                                                      const float* __restrict__ PartB,
                                                      const float* __restrict__ PartL,
                                                      bf16_t* __restrict__ Og) {
    const int qc = blockIdx.x, bh = blockIdx.y;   // qc 0..7
    const int b = bh >> 4, h = bh & 15;
    const int t0 = (bh * 8 + qc) * 2;             // even; pair never straddles 384
    const float* p0 = (t0 < 384) ? (PartA + (size_t)t0 * 32768)
                                 : (PartB + (size_t)(t0 - 384) * 32768);
    const float* p1 = (t0 + 1 < 384) ? (PartA + (size_t)(t0 + 1) * 32768)
                                     : (PartB + (size_t)(t0 + 1 - 384) * 32768);
    __shared__ float invl[256];
    const int tid = threadIdx.x;
    invl[tid] = 1.0f / (PartL[(size_t)t0 * 256 + tid] + PartL[(size_t)(t0 + 1) * 256 + tid]);
    __syncthreads();
    const int qbase = (4 + qc) * 256;
#pragma unroll
    for (int j = 0; j < 32; j++) {
        int idx = j * 1024 + tid * 4;             // flat f32 index in 256x128 tile
        int q = idx >> 7, d = idx & 127;
        f32x4 a = *(const f32x4*)(p0 + idx);
        f32x4 c4 = *(const f32x4*)(p1 + idx);
        float inv = invl[q];
        bf16x4 ov;
#pragma unroll
        for (int i = 0; i < 4; i++) ov[i] = (bf16_t)((a[i] + c4[i]) * inv);
        *(bf16x4*)(Og + (((size_t)b * NS + qbase + q) * NH + h) * NHD + d) = ov;
    }
}

// ---------------------------------------------------------------------------
extern "C" void kernel_launch(void* const* d_in, const int* in_sizes, int n_in,
                              void* d_out, int out_size, void* d_ws, size_t ws_size,
                              hipStream_t stream) {
    const float* hs  = (const float*)d_in[0];
    const float* rot = (const float*)d_in[1];
    const float* Wq  = (const float*)d_in[2];
    const float* bq  = (const float*)d_in[3];
    const float* Wk  = (const float*)d_in[4];
    const float* bk  = (const float*)d_in[5];
    const float* Wv  = (const float*)d_in[6];
    const float* bv  = (const float*)d_in[7];
    const float* gq  = (const float*)d_in[8];
    const float* gk  = (const float*)d_in[9];
    const float* Wo  = (const float*)d_in[10];
    const float* bo  = (const float*)d_in[11];
    float* out = (float*)d_out;

    // ws map (high-water 146800640 B):
    //   0        .. 25165824  Xb (hs bf16)            [dead after QKV GEMM; Ob]
    //   25165824 .. 50331648  Wqkv bf16               [dead after QKV GEMM]
    //   50331648 .. 58720256  Wo bf16                 [live until final GEMM]
    //   58720256 ..134217728  QKVb bf16 [6144][6144]
    //  134217728 ..146800640  VTb [bh][d][s]
    // Attention-time reuse:
    //   Ob    = ws[0..25165824)
    //   PartB = ws[25165824..41943040)   128 tiles x 131072 B
    //   PartL = ws[41943040..42467328)   512 tiles x 256 f32
    //   PartA = d_out (384 tiles x 131072 B = 50331648 exactly)
    char* ws = (char*)d_ws;
    bf16_t* Xb    = (bf16_t*)(ws + 0);
    bf16_t* Wqkvb = (bf16_t*)(ws + 25165824);
    bf16_t* Wob   = (bf16_t*)(ws + 50331648);
    bf16_t* QKVb  = (bf16_t*)(ws + 58720256);
    bf16_t* VTb   = (bf16_t*)(ws + 134217728);
    bf16_t* Ob    = (bf16_t*)(ws + 0);
    float*  PartB = (float*)(ws + 25165824);
    float*  PartL = (float*)(ws + 41943040);
    float*  Psum  = out;                          // 6144*96*4 = 2359296 B
    float*  bqkv  = (float*)((char*)d_out + 3145728);
    float*  PartA = out;

    const float QSCALE = 1.4426950408889634f * 0.08838834764831845f; // log2(e)/sqrt(128)

    // 1. casts + bias concat
    cast_bf16_kernel<<<12288, 256, 0, stream>>>(hs, Xb, NTOK * ND / 4);
    cast_bf16_kernel<<<4096, 256, 0, stream>>>(Wq, Wqkvb, ND * ND / 4);
    cast_bf16_kernel<<<4096, 256, 0, stream>>>(Wk, Wqkvb + (size_t)ND * ND, ND * ND / 4);
    cast_bf16_kernel<<<4096, 256, 0, stream>>>(Wv, Wqkvb + (size_t)2 * ND * ND, ND * ND / 4);
    cast_bf16_kernel<<<4096, 256, 0, stream>>>(Wo, Wob, ND * ND / 4);
    bias_concat_kernel<<<24, 256, 0, stream>>>(bq, bk, bv, bqkv);

    // 2. fused QKV projection: 256^2 8-phase counted-vmcnt GEMM (576 blocks)
    gemm256<1><<<dim3(N3 / 256, NTOK / 256), 512, 0, stream>>>(Xb, Wqkvb, bqkv,
                                                               (void*)QKVb, Psum,
                                                               N3, ND);
    // 3. in-place RMSNorm + RoPE on Q,K segments
    rmsrope2_kernel<<<NTOK, 256, 0, stream>>>(QKVb, Psum, gq, gk, rot, QSCALE);
    // 4. V transpose
    vtrans_kernel<<<dim3(48, 32), 256, 0, stream>>>(QKVb, VTb);
    // 5. attention (256q blocks, 64q/wave, async K/V staging) + combine
    attn_kernel<<<dim3(20, 32), 256, 0, stream>>>(QKVb, VTb, Ob, PartA, PartB, PartL);
    combine_kernel<<<dim3(8, 32), 256, 0, stream>>>(PartA, PartB, PartL, Ob);
    // 6. output projection: 256^2 template (192 blocks)
    gemm256<0><<<dim3(ND / 256, NTOK / 256), 512, 0, stream>>>(Ob, Wob, bo,
                                                               (void*)out, nullptr,
                                                               ND, ND);
}

// Round 5
// 680.767 us; speedup vs baseline: 1.3521x; 1.3521x over previous
//
#include <hip/hip_runtime.h>
#include <cstdint>
#include <cstddef>

// ---------------------------------------------------------------------------
// HeliosAttention: hs->fused QKV proj(bf16 out + sumsq partials) -> in-place
// RMSNorm+RoPE -> 2-segment SDPA (S^T flash, fixed-max softmax, balanced
// chunks) -> out proj.  B=2 S=3072 DIM=2048 H=16 HD=128 hist=1024
// R9 == R7/R8 resubmit (two container-level infra failures; static audit of
// swizzle changes passes: no OOB, no divergent barriers, R5-identical global
// addressing).  If this fails a third time, next round submits byte-exact R5
// to discriminate kernel-triggered container death from infra.
// R7: attention = R5 structure (register prefetch, 128q/block, 3 blocks/CU);
// LDS layouts linear stride + XOR granule swizzle (granule ^= row&7, 16B
// granules) on Ks/Vs/Ps write+read to kill stride-272/144 bank aliasing
// (R5: 2.75e7 conflict cycles/dispatch).
// GEMMs: 256x256 8-phase counted-vmcnt template (R5, unchanged).
// ---------------------------------------------------------------------------

typedef __bf16 bf16_t;
typedef __attribute__((ext_vector_type(8))) __bf16 bf16x8;
typedef __attribute__((ext_vector_type(4))) __bf16 bf16x4;
typedef __attribute__((ext_vector_type(4))) float f32x4;
typedef __attribute__((ext_vector_type(4))) unsigned int u32x4;

#define NB   2
#define NS   3072
#define ND   2048
#define NH   16
#define NHD  128
#define NTOK (NB * NS)      // 6144
#define NHIST 1024
#define N3   (3 * ND)       // 6144 fused QKV row width

__device__ __forceinline__ f32x4 mfma16(bf16x8 a, bf16x8 b, f32x4 c) {
    return __builtin_amdgcn_mfma_f32_16x16x32_bf16(a, b, c, 0, 0, 0);
}

// async global->LDS, 16B per lane. LDS dst MUST be wave-uniform base + lane*16.
__device__ __forceinline__ void async16(const bf16_t* gsrc, bf16_t* ldst) {
    __builtin_amdgcn_global_load_lds(
        (const __attribute__((address_space(1))) void*)gsrc,
        (__attribute__((address_space(3))) void*)ldst,
        16, 0, 0);
}

// ---------------- fp32 -> bf16 elementwise cast ----------------
__global__ __launch_bounds__(256) void cast_bf16_kernel(const float* __restrict__ src,
                                                        bf16_t* __restrict__ dst, int n4) {
    int i = blockIdx.x * 256 + threadIdx.x;
    if (i >= n4) return;
    f32x4 v = ((const f32x4*)src)[i];
    bf16x4 o;
    o[0] = (bf16_t)v[0]; o[1] = (bf16_t)v[1];
    o[2] = (bf16_t)v[2]; o[3] = (bf16_t)v[3];
    ((bf16x4*)dst)[i] = o;
}

// ---------------- concat bq|bk|bv -> 6144 floats ----------------
__global__ __launch_bounds__(256) void bias_concat_kernel(const float* __restrict__ bq,
                                                          const float* __restrict__ bk,
                                                          const float* __restrict__ bv,
                                                          float* __restrict__ dst) {
    int i = blockIdx.x * 256 + threadIdx.x;
    if (i >= N3) return;
    dst[i] = (i < ND) ? bq[i] : (i < 2 * ND ? bk[i - ND] : bv[i - 2 * ND]);
}

// ---------------------------------------------------------------------------
// 256x256 tile GEMM, C = A * B^T + bias (R5 8-phase counted-vmcnt template).
// MODE 1: bf16 C + fp32 sumsq partials (QKV).  MODE 0: f32 C (O-proj).
// ---------------------------------------------------------------------------
template<int MODE>
__global__ __launch_bounds__(512, 2) void gemm256(const bf16_t* __restrict__ A,
                                                  const bf16_t* __restrict__ Bm,
                                                  const float* __restrict__ bias,
                                                  void* __restrict__ Cout,
                                                  float* __restrict__ Psum,
                                                  int N, int K) {
    __shared__ __align__(16) char smem[131072];
    const int tid  = threadIdx.x;
    const int wid  = tid >> 6, lane = tid & 63;
    const int g    = lane >> 4, c = lane & 15;
    const int wr   = wid >> 2, wc = wid & 3;

    const int gx = gridDim.x, gy = gridDim.y;
    const int nwg = gx * gy;
    const int bid = blockIdx.y * gx + blockIdx.x;
    const int cpx = nwg >> 3;
    const int swz = (bid & 7) * cpx + (bid >> 3);
    const int bx = swz / gy, by = swz % gy;
    const int m0 = by * 256, n0 = bx * 256;

    const int r0 = tid >> 2, sq = tid & 3;
    const int sd = sq ^ ((r0 >> 1) & 3);
    const bf16_t* At = A  + (size_t)(m0 + r0) * K + sd * 8;
    const bf16_t* Bt = Bm + (size_t)(n0 + r0) * K + sd * 8;
    const size_t rs128 = (size_t)128 * K;

    const int axor = ((c >> 1) & 3) << 4;
    const int gb   = (g << 4) ^ axor;
    const int aRow = (wr * 128 + c) * 64 + gb;
    const int bRow = 32768 + (wc * 64 + c) * 64 + gb;

    f32x4 acc[8][4];
#pragma unroll
    for (int i = 0; i < 8; i++)
#pragma unroll
        for (int j = 0; j < 4; j++) acc[i][j] = (f32x4){0.f, 0.f, 0.f, 0.f};

    auto stA = [&](int kt, int kh, int db) {
        const bf16_t* s = At + (size_t)kt * 64 + kh * 32;
        char* d = smem + db * 65536 + kh * 16384 + tid * 16;
        async16(s, (bf16_t*)d);
        async16(s + rs128, (bf16_t*)(d + 8192));
    };
    auto stB = [&](int kt, int kh, int db) {
        const bf16_t* s = Bt + (size_t)kt * 64 + kh * 32;
        char* d = smem + db * 65536 + 32768 + kh * 16384 + tid * 16;
        async16(s, (bf16_t*)d);
        async16(s + rs128, (bf16_t*)(d + 8192));
    };

    const int nkt = K >> 6;
    stA(0, 0, 0); stB(0, 0, 0); stA(0, 1, 0); stB(0, 1, 0);
    stA(1, 0, 1); stB(1, 0, 1);
    asm volatile("s_waitcnt vmcnt(4)" ::: "memory");
    __builtin_amdgcn_s_barrier();
    asm volatile("" ::: "memory");

    auto tile = [&](int t, int db) {
        const int kt1 = (t + 1 < nkt) ? t + 1 : 0;
        const int kt2 = (t + 2 < nkt) ? t + 2 : 0;
        const char* base = smem + db * 65536;
        bf16x8 Bf[4], Af[4];
#pragma unroll
        for (int ph = 0; ph < 4; ph++) {
            const int ks = ph >> 1, mh = ph & 1;
            if (mh == 0) {
#pragma unroll
                for (int ni = 0; ni < 4; ni++)
                    Bf[ni] = *(const bf16x8*)(base + ks * 16384 + ni * 1024 + bRow);
            }
#pragma unroll
            for (int r4 = 0; r4 < 4; r4++)
                Af[r4] = *(const bf16x8*)(base + ks * 16384 + (mh * 4 + r4) * 1024 + aRow);
            if (ph == 0)      stA(kt1, 1, db ^ 1);
            else if (ph == 1) stB(kt1, 1, db ^ 1);
            else if (ph == 2) stA(kt2, 0, db);
            else {            stB(kt2, 0, db);
                              asm volatile("s_waitcnt vmcnt(4)" ::: "memory"); }
            asm volatile("" ::: "memory");
            __builtin_amdgcn_s_barrier();
            asm volatile("" ::: "memory");
            __builtin_amdgcn_s_setprio(1);
#pragma unroll
            for (int r4 = 0; r4 < 4; r4++)
#pragma unroll
                for (int ni = 0; ni < 4; ni++)
                    acc[mh * 4 + r4][ni] = mfma16(Af[r4], Bf[ni], acc[mh * 4 + r4][ni]);
            __builtin_amdgcn_s_setprio(0);
            asm volatile("" ::: "memory");
            __builtin_amdgcn_s_barrier();
            asm volatile("" ::: "memory");
        }
    };

#pragma unroll 1
    for (int t = 0; t < nkt; t += 2) { tile(t, 0); tile(t + 1, 1); }

    asm volatile("s_waitcnt vmcnt(0)" ::: "memory");

    float bi[4];
#pragma unroll
    for (int ni = 0; ni < 4; ni++) bi[ni] = bias[n0 + wc * 64 + ni * 16 + c];
    if (MODE == 1) {
        bf16_t* C = (bf16_t*)Cout;
        const int grp = (n0 >> 6) + wc;
#pragma unroll
        for (int mi = 0; mi < 8; mi++) {
#pragma unroll
            for (int i = 0; i < 4; i++) {
                int m = m0 + wr * 128 + mi * 16 + g * 4 + i;
                bf16_t* crow = C + (size_t)m * N + n0 + wc * 64 + c;
                float s = 0.f;
#pragma unroll
                for (int ni = 0; ni < 4; ni++) {
                    float v = acc[mi][ni][i] + bi[ni];
                    crow[ni * 16] = (bf16_t)v;
                    s += v * v;
                }
#pragma unroll
                for (int msk = 1; msk < 16; msk <<= 1) s += __shfl_xor(s, msk);
                if (c == 0) Psum[(size_t)m * 96 + grp] = s;
            }
        }
    } else {
        float* C = (float*)Cout;
#pragma unroll
        for (int mi = 0; mi < 8; mi++) {
#pragma unroll
            for (int i = 0; i < 4; i++) {
                int m = m0 + wr * 128 + mi * 16 + g * 4 + i;
                float* crow = C + (size_t)m * N + n0 + wc * 64 + c;
#pragma unroll
                for (int ni = 0; ni < 4; ni++) crow[ni * 16] = acc[mi][ni][i] + bi[ni];
            }
        }
    }
}

// ---------------- in-place RMSNorm + RoPE on bf16 QKV rows ----------------
__global__ __launch_bounds__(256) void rmsrope2_kernel(bf16_t* __restrict__ QKV,
                                                       const float* __restrict__ Psum,
                                                       const float* __restrict__ gq,
                                                       const float* __restrict__ gk,
                                                       const float* __restrict__ rot,
                                                       float qscale) {
    const int t = blockIdx.x;
    const int s = t % NS;
    const int tid = threadIdx.x;
    __shared__ float sh[2];
    float p = 0.f;
    if (tid < 64) p = Psum[(size_t)t * 96 + tid];
#pragma unroll
    for (int msk = 1; msk < 32; msk <<= 1) p += __shfl_xor(p, msk);
    if (tid == 0) sh[0] = p;
    if (tid == 32) sh[1] = p;
    __syncthreads();
    const float sclQ = rsqrtf(sh[0] * (1.f / (float)ND) + 1e-6f);
    const float sclK = rsqrtf(sh[1] * (1.f / (float)ND) + 1e-6f);

    const int col = tid * 8, hd = col & (NHD - 1);
    const float* rr = rot + (size_t)s * (2 * NHD);
    float cc[4], sn[4];
#pragma unroll
    for (int u = 0; u < 4; u++) {
        cc[u] = rr[hd + 2 * u];
        sn[u] = rr[NHD + hd + 2 * u + 1];
    }
    bf16_t* row = QKV + (size_t)t * N3;

    bf16x8 xq = *(bf16x8*)(row + col);
    bf16x8 xk = *(bf16x8*)(row + ND + col);
    bf16x8 oq, ok;
#pragma unroll
    for (int u = 0; u < 4; u++) {
        float e  = (float)xq[2 * u]     * sclQ * gq[col + 2 * u];
        float od = (float)xq[2 * u + 1] * sclQ * gq[col + 2 * u + 1];
        oq[2 * u]     = (bf16_t)((e * cc[u] - od * sn[u]) * qscale);
        oq[2 * u + 1] = (bf16_t)((e * sn[u] + od * cc[u]) * qscale);
        float ek  = (float)xk[2 * u]     * sclK * gk[col + 2 * u];
        float odk = (float)xk[2 * u + 1] * sclK * gk[col + 2 * u + 1];
        ok[2 * u]     = (bf16_t)(ek * cc[u] - odk * sn[u]);
        ok[2 * u + 1] = (bf16_t)(ek * sn[u] + odk * cc[u]);
    }
    *(bf16x8*)(row + col) = oq;
    *(bf16x8*)(row + ND + col) = ok;
}

// ---------------- V transpose: QKV bf16 V-cols -> [bh][d][s] ----------------
__global__ __launch_bounds__(256) void vtrans_kernel(const bf16_t* __restrict__ QKV,
                                                     bf16_t* __restrict__ VTg) {
    __shared__ bf16_t T[128 * 65];
    const int tid = threadIdx.x;
    const int st = blockIdx.x;
    const int bh = blockIdx.y;
    const int b = bh >> 4, h = bh & 15;
    const int ds = tid >> 4, ssx = tid & 15;
#pragma unroll
    for (int i = 0; i < 4; i++) {
        int sl = ssx + i * 16;
        const bf16_t* xr = QKV + (size_t)(b * NS + st * 64 + sl) * N3 + 2 * ND + h * NHD;
        bf16x8 v = *(const bf16x8*)(xr + ds * 8);
#pragma unroll
        for (int u = 0; u < 8; u++) T[(ds * 8 + u) * 65 + sl] = v[u];
    }
    __syncthreads();
#pragma unroll
    for (int q = 0; q < 4; q++) {
        int chunk = q * 256 + tid;
        int d = chunk >> 3, sc8 = chunk & 7;
        bf16x8 o;
#pragma unroll
        for (int u = 0; u < 8; u++) o[u] = T[d * 65 + sc8 * 8 + u];
        *(bf16x8*)(VTg + ((size_t)bh * NHD + d) * NS + st * 64 + sc8 * 8) = o;
    }
}

// ---------------- flash attention (R5 structure + swizzled LDS) -------------
// S^T trick, fixed-max softmax, balanced key chunks, 64-key iters, register
// prefetch depth 1, single per-wave Ps.  LDS: linear strides (Ks 256B,
// Vs/Ps 128B rows) with 16B-granule XOR swizzle  granule ^= (row & 7)
// applied on BOTH write and read (bijective per row; kills the 8-way
// start-bank aliasing of the old 272/144B strides).
__global__ __launch_bounds__(256, 3) void attn_kernel(const bf16_t* __restrict__ QKV,
                                                      const bf16_t* __restrict__ Vg,
                                                      bf16_t* __restrict__ Og,
                                                      float* __restrict__ PartA,
                                                      float* __restrict__ PartB,
                                                      float* __restrict__ PartL) {
    __shared__ bf16_t Ks[64 * 128];       // [key][d] linear (16384 B)
    __shared__ bf16_t Vs[128 * 64];       // [d][key] linear (16384 B)
    __shared__ bf16_t Ps[4][16 * 64];     // per-wave P [q][key] (8192 B)
    const int tid = threadIdx.x;
    const int wid = tid >> 6, lane = tid & 63;
    const int g = lane >> 4, c = lane & 15;
    const int x = blockIdx.x, bh = blockIdx.y;
    const int b = bh >> 4, h = bh & 15;
    const float FM = 18.0f;

    int qb, k0, niter, tile;
    bool direct;
    if (x < 8) { qb = x; k0 = 0; niter = 16; direct = true; tile = 0; }
    else {
        int t = x - 8;
        qb = 8 + (t >> 1);
        int ch = t & 1;
        k0 = ch * 1536; niter = 24; direct = false;
        tile = (bh * 16 + (qb - 8)) * 2 + ch;      // 0..1023
    }
    const int q0 = qb * 128 + wid * 32;

    // Q B-fragments for 2 q-subtiles, held in registers for the whole kernel
    bf16x8 qf[2][4];
#pragma unroll
    for (int f = 0; f < 2; f++) {
        const bf16_t* qrow = QKV + (size_t)(b * NS + q0 + f * 16 + c) * N3 + h * NHD;
#pragma unroll
        for (int d = 0; d < 4; d++) qf[f][d] = *(const bf16x8*)(qrow + d * 32 + g * 8);
    }

    f32x4 o[2][8];
#pragma unroll
    for (int f = 0; f < 2; f++)
#pragma unroll
        for (int nt = 0; nt < 8; nt++) o[f][nt] = (f32x4){0.f, 0.f, 0.f, 0.f};
    float l[2] = {0.f, 0.f};

    // staging assignments (64-key tiles)
    const int skrow = tid >> 2, skc = tid & 3;    // K: 64 rows x 4 chunks of 8 elem
    const int svd = tid >> 1, svc = tid & 1;      // V: 128 rows x 2 chunks of 8 keys
    const bf16_t* kbase = QKV + (size_t)(b * NS + skrow) * N3 + ND + h * NHD;
    const bf16_t* vbase = Vg + ((size_t)bh * NHD + svd) * NS;
    bf16_t* pw = &Ps[wid][0];
    const int c7 = c & 7;

    u32x4 kreg[4], vreg[4];
    {   // preload iteration 0
        const u32x4* ks = (const u32x4*)(kbase + (size_t)k0 * N3);
        const u32x4* vs = (const u32x4*)(vbase + k0);
#pragma unroll
        for (int j = 0; j < 4; j++) { kreg[j] = ks[skc + 4 * j]; vreg[j] = vs[svc + 2 * j]; }
    }

    for (int it = 0; it < niter; it++) {
        __syncthreads();    // previous iteration's LDS readers done
#pragma unroll
        for (int j = 0; j < 4; j++) {
            *(u32x4*)&Ks[skrow * 128 + (((skc + 4 * j) ^ (skrow & 7)) * 8)] = kreg[j];
            *(u32x4*)&Vs[svd * 64 + (((svc + 2 * j) ^ (svd & 7)) * 8)]      = vreg[j];
        }
        __syncthreads();
        if (it + 1 < niter) {       // prefetch next tile; latency overlaps compute
            const int kb = k0 + (it + 1) * 64;
            const u32x4* ks = (const u32x4*)(kbase + (size_t)kb * N3);
            const u32x4* vs = (const u32x4*)(vbase + kb);
#pragma unroll
            for (int j = 0; j < 4; j++) { kreg[j] = ks[skc + 4 * j]; vreg[j] = vs[svc + 2 * j]; }
        }

        // S^T = mfma(K-frag, Q-frag): S[q=q0+f*16+c][key = kt*16 + g*4 + i]
        f32x4 sv[2][4];
#pragma unroll
        for (int f = 0; f < 2; f++)
#pragma unroll
            for (int kt = 0; kt < 4; kt++) sv[f][kt] = (f32x4){0.f, 0.f, 0.f, 0.f};
#pragma unroll
        for (int kt = 0; kt < 4; kt++)
#pragma unroll
            for (int dd = 0; dd < 4; dd++) {
                bf16x8 kf = *(const bf16x8*)&Ks[(kt * 16 + c) * 128 + (((dd * 4 + g) ^ c7) * 8)];
#pragma unroll
                for (int f = 0; f < 2; f++) sv[f][kt] = mfma16(kf, qf[f][dd], sv[f][kt]);
            }

        // fixed-max softmax p = exp2(s-FM); l per-lane (deferred reduction).
        bf16x8 pf[2][2];
#pragma unroll
        for (int f = 0; f < 2; f++) {
#pragma unroll
            for (int kt = 0; kt < 4; kt++) {
                bf16x4 pk;
#pragma unroll
                for (int i = 0; i < 4; i++) {
                    float pv = exp2f(sv[f][kt][i] - FM);
                    l[f] += pv;
                    pk[i] = (bf16_t)pv;
                }
                *(bf16x4*)&pw[c * 64 + (((kt * 2 + (g >> 1)) ^ c7) * 8) + (g & 1) * 4] = pk;
            }
#pragma unroll
            for (int s = 0; s < 2; s++)
                pf[f][s] = *(const bf16x8*)&pw[c * 64 + (((s * 4 + g) ^ c7) * 8)];
        }

        // O^T += mfma(V^T-frag, P-frag), contraction over 64 keys
#pragma unroll
        for (int s = 0; s < 2; s++)
#pragma unroll
            for (int nt = 0; nt < 8; nt++) {
                bf16x8 vf = *(const bf16x8*)&Vs[(nt * 16 + c) * 64 + (((s * 4 + g) ^ c7) * 8)];
                o[0][nt] = mfma16(vf, pf[0][s], o[0][nt]);
                o[1][nt] = mfma16(vf, pf[1][s], o[1][nt]);
            }
    }

    if (direct) {
        // reduce l over g-groups, normalize, store bf16 [b][s][h][d]
#pragma unroll
        for (int f = 0; f < 2; f++) {
            float lt = l[f];
            lt += __shfl_xor(lt, 16);
            lt += __shfl_xor(lt, 32);
            float inv = 1.0f / lt;
            bf16_t* orow = Og + (((size_t)b * NS + q0 + f * 16 + c) * NH + h) * NHD;
#pragma unroll
            for (int nt = 0; nt < 8; nt++) {
                bf16x4 ov;
#pragma unroll
                for (int i = 0; i < 4; i++) ov[i] = (bf16_t)(o[f][nt][i] * inv);
                *(bf16x4*)(orow + nt * 16 + g * 4) = ov;
            }
        }
    } else {
        // write unnormalized f32 partial tile [q 0..127][d 0..127] + l partials
        float* pt = (tile < 768) ? (PartA + (size_t)tile * 16384)
                                 : (PartB + (size_t)(tile - 768) * 16384);
#pragma unroll
        for (int f = 0; f < 2; f++) {
            float lt = l[f];
            lt += __shfl_xor(lt, 16);
            lt += __shfl_xor(lt, 32);
            if (g == 0) PartL[(size_t)tile * 128 + wid * 32 + f * 16 + c] = lt;
            float* prow = pt + (wid * 32 + f * 16 + c) * 128;
#pragma unroll
            for (int nt = 0; nt < 8; nt++)
                *(f32x4*)(prow + nt * 16 + g * 4) = o[f][nt];
        }
    }
}

// ---------------- combine: sum 2 chunk partials, normalize, write bf16 Ob ----
__global__ __launch_bounds__(256) void combine_kernel(const float* __restrict__ PartA,
                                                      const float* __restrict__ PartB,
                                                      const float* __restrict__ PartL,
                                                      bf16_t* __restrict__ Og) {
    const int qc = blockIdx.x, bh = blockIdx.y;
    const int b = bh >> 4, h = bh & 15;
    const int t0 = (bh * 16 + qc) * 2;            // even; pair never straddles 768
    const float* p0 = (t0 < 768) ? (PartA + (size_t)t0 * 16384)
                                 : (PartB + (size_t)(t0 - 768) * 16384);
    const float* p1 = (t0 + 1 < 768) ? (PartA + (size_t)(t0 + 1) * 16384)
                                     : (PartB + (size_t)(t0 + 1 - 768) * 16384);
    __shared__ float invl[128];
    const int tid = threadIdx.x;
    if (tid < 128)
        invl[tid] = 1.0f / (PartL[(size_t)t0 * 128 + tid] + PartL[(size_t)(t0 + 1) * 128 + tid]);
    __syncthreads();
    const int qb = 8 + qc;
#pragma unroll
    for (int j = 0; j < 16; j++) {
        int idx = j * 1024 + tid * 4;             // flat f32 index in 128x128 tile
        int q = idx >> 7, d = idx & 127;
        f32x4 a = *(const f32x4*)(p0 + idx);
        f32x4 c4 = *(const f32x4*)(p1 + idx);
        float inv = invl[q];
        bf16x4 ov;
#pragma unroll
        for (int i = 0; i < 4; i++) ov[i] = (bf16_t)((a[i] + c4[i]) * inv);
        *(bf16x4*)(Og + (((size_t)b * NS + qb * 128 + q) * NH + h) * NHD + d) = ov;
    }
}

// ---------------------------------------------------------------------------
extern "C" void kernel_launch(void* const* d_in, const int* in_sizes, int n_in,
                              void* d_out, int out_size, void* d_ws, size_t ws_size,
                              hipStream_t stream) {
    const float* hs  = (const float*)d_in[0];
    const float* rot = (const float*)d_in[1];
    const float* Wq  = (const float*)d_in[2];
    const float* bq  = (const float*)d_in[3];
    const float* Wk  = (const float*)d_in[4];
    const float* bk  = (const float*)d_in[5];
    const float* Wv  = (const float*)d_in[6];
    const float* bv  = (const float*)d_in[7];
    const float* gq  = (const float*)d_in[8];
    const float* gk  = (const float*)d_in[9];
    const float* Wo  = (const float*)d_in[10];
    const float* bo  = (const float*)d_in[11];
    float* out = (float*)d_out;

    // ws map (high-water 146800640 B):
    //   0        .. 25165824  Xb (hs bf16)            [dead after QKV GEMM; Ob]
    //   25165824 .. 50331648  Wqkv bf16               [dead after QKV GEMM]
    //   50331648 .. 58720256  Wo bf16                 [live until final GEMM]
    //   58720256 ..134217728  QKVb bf16 [6144][6144]
    //  134217728 ..146800640  VTb [bh][d][s]
    // Attention-time reuse:
    //   Ob    = ws[0..12.6MB)       (Xb region)
    //   PartB = ws[25165824..42MB)  (Wqkv region, 256 tiles)
    //   PartL = ws[41943040..42.5MB)
    //   PartA = d_out (768 tiles x 65536 B = 50331648 exactly)
    char* ws = (char*)d_ws;
    bf16_t* Xb    = (bf16_t*)(ws + 0);
    bf16_t* Wqkvb = (bf16_t*)(ws + 25165824);
    bf16_t* Wob   = (bf16_t*)(ws + 50331648);
    bf16_t* QKVb  = (bf16_t*)(ws + 58720256);
    bf16_t* VTb   = (bf16_t*)(ws + 134217728);
    bf16_t* Ob    = (bf16_t*)(ws + 0);
    float*  PartB = (float*)(ws + 25165824);
    float*  PartL = (float*)(ws + 41943040);
    float*  Psum  = out;                          // 6144*96*4 = 2359296 B
    float*  bqkv  = (float*)((char*)d_out + 3145728);
    float*  PartA = out;

    const float QSCALE = 1.4426950408889634f * 0.08838834764831845f; // log2(e)/sqrt(128)

    // 1. casts + bias concat
    cast_bf16_kernel<<<12288, 256, 0, stream>>>(hs, Xb, NTOK * ND / 4);
    cast_bf16_kernel<<<4096, 256, 0, stream>>>(Wq, Wqkvb, ND * ND / 4);
    cast_bf16_kernel<<<4096, 256, 0, stream>>>(Wk, Wqkvb + (size_t)ND * ND, ND * ND / 4);
    cast_bf16_kernel<<<4096, 256, 0, stream>>>(Wv, Wqkvb + (size_t)2 * ND * ND, ND * ND / 4);
    cast_bf16_kernel<<<4096, 256, 0, stream>>>(Wo, Wob, ND * ND / 4);
    bias_concat_kernel<<<24, 256, 0, stream>>>(bq, bk, bv, bqkv);

    // 2. fused QKV projection: 256^2 8-phase counted-vmcnt GEMM (576 blocks)
    gemm256<1><<<dim3(N3 / 256, NTOK / 256), 512, 0, stream>>>(Xb, Wqkvb, bqkv,
                                                               (void*)QKVb, Psum,
                                                               N3, ND);
    // 3. in-place RMSNorm + RoPE on Q,K segments
    rmsrope2_kernel<<<NTOK, 256, 0, stream>>>(QKVb, Psum, gq, gk, rot, QSCALE);
    // 4. V transpose
    vtrans_kernel<<<dim3(48, 32), 256, 0, stream>>>(QKVb, VTb);
    // 5. attention (balanced chunks, 64-key iters, prefetch) + combine
    attn_kernel<<<dim3(40, 32), 256, 0, stream>>>(QKVb, VTb, Ob, PartA, PartB, PartL);
    combine_kernel<<<dim3(16, 32), 256, 0, stream>>>(PartA, PartB, PartL, Ob);
    // 6. output projection: 256^2 template (192 blocks)
    gemm256<0><<<dim3(ND / 256, NTOK / 256), 512, 0, stream>>>(Ob, Wob, bo,
                                                               (void*)out, nullptr,
                                                               ND, ND);
}

// Round 6
// 641.434 us; speedup vs baseline: 1.4350x; 1.0613x over previous
//
#include <hip/hip_runtime.h>
#include <cstdint>
#include <cstddef>

// ---------------------------------------------------------------------------
// HeliosAttention: hs->fused QKV proj(bf16 out + sumsq partials) -> in-place
// RMSNorm+RoPE -> 2-segment SDPA (S^T flash, fixed-max softmax, balanced
// chunks) -> out proj.  B=2 S=3072 DIM=2048 H=16 HD=128 hist=1024
// R10: attn reverted to byte-exact R5 (swizzle A/B came back negative:
// conflicts -33% but dur +15% -- address-chain cost > conflict savings).
// gemm256: per-tile vmcnt(4) moved p3 -> p1 end; kh1 latency cover grows
// from ~2-3 phases to ~5-6 (the suspected ~500cyc/K-tile stall).
// ---------------------------------------------------------------------------

typedef __bf16 bf16_t;
typedef __attribute__((ext_vector_type(8))) __bf16 bf16x8;
typedef __attribute__((ext_vector_type(4))) __bf16 bf16x4;
typedef __attribute__((ext_vector_type(4))) float f32x4;
typedef __attribute__((ext_vector_type(4))) unsigned int u32x4;

#define NB   2
#define NS   3072
#define ND   2048
#define NH   16
#define NHD  128
#define NTOK (NB * NS)      // 6144
#define NHIST 1024
#define N3   (3 * ND)       // 6144 fused QKV row width

__device__ __forceinline__ f32x4 mfma16(bf16x8 a, bf16x8 b, f32x4 c) {
    return __builtin_amdgcn_mfma_f32_16x16x32_bf16(a, b, c, 0, 0, 0);
}

// async global->LDS, 16B per lane. LDS dst MUST be wave-uniform base + lane*16.
__device__ __forceinline__ void async16(const bf16_t* gsrc, bf16_t* ldst) {
    __builtin_amdgcn_global_load_lds(
        (const __attribute__((address_space(1))) void*)gsrc,
        (__attribute__((address_space(3))) void*)ldst,
        16, 0, 0);
}

// ---------------- fp32 -> bf16 elementwise cast ----------------
__global__ __launch_bounds__(256) void cast_bf16_kernel(const float* __restrict__ src,
                                                        bf16_t* __restrict__ dst, int n4) {
    int i = blockIdx.x * 256 + threadIdx.x;
    if (i >= n4) return;
    f32x4 v = ((const f32x4*)src)[i];
    bf16x4 o;
    o[0] = (bf16_t)v[0]; o[1] = (bf16_t)v[1];
    o[2] = (bf16_t)v[2]; o[3] = (bf16_t)v[3];
    ((bf16x4*)dst)[i] = o;
}

// ---------------- concat bq|bk|bv -> 6144 floats ----------------
__global__ __launch_bounds__(256) void bias_concat_kernel(const float* __restrict__ bq,
                                                          const float* __restrict__ bk,
                                                          const float* __restrict__ bv,
                                                          float* __restrict__ dst) {
    int i = blockIdx.x * 256 + threadIdx.x;
    if (i >= N3) return;
    dst[i] = (i < ND) ? bq[i] : (i < 2 * ND ? bk[i - ND] : bv[i - 2 * ND]);
}

// ---------------------------------------------------------------------------
// 256x256 tile GEMM, C = A * B^T + bias.  BK=64, 8 waves (2Mx4N), per-wave
// 128x64 output.  128 KiB LDS double-buffered; stage unit = (matrix, k-half)
// = 256x32 bf16 via 2x global_load_lds w16/thread.  4 phases per K-tile;
// ONE vmcnt(4) per K-tile at END OF P1 (R10: moved from p3):
//   outstanding there = {t-kh1, t+1-kh0, t+1-kh1} (12 ops); wait->4 drains
//   t-kh1 (needed at p2, issued t-1.p0: 5-6 phase cover) and t+1-kh0
//   (needed t+1.p0, issued t-1.p2: 3-4 phase cover); t+1-kh1 stays in
//   flight.  Issue points unchanged -> write-after-read windows unchanged.
// LDS slot swizzle s' = s ^ ((row>>1)&3) on 16B slots, applied on the
// global SOURCE (inverse) and on ds_read (both-sides rule).
// MODE 1: bf16 C + fp32 sumsq partials (QKV).  MODE 0: f32 C (O-proj).
// ---------------------------------------------------------------------------
template<int MODE>
__global__ __launch_bounds__(512, 2) void gemm256(const bf16_t* __restrict__ A,
                                                  const bf16_t* __restrict__ Bm,
                                                  const float* __restrict__ bias,
                                                  void* __restrict__ Cout,
                                                  float* __restrict__ Psum,
                                                  int N, int K) {
    __shared__ __align__(16) char smem[131072];
    const int tid  = threadIdx.x;
    const int wid  = tid >> 6, lane = tid & 63;
    const int g    = lane >> 4, c = lane & 15;
    const int wr   = wid >> 2, wc = wid & 3;

    const int gx = gridDim.x, gy = gridDim.y;
    const int nwg = gx * gy;
    const int bid = blockIdx.y * gx + blockIdx.x;
    const int cpx = nwg >> 3;
    const int swz = (bid & 7) * cpx + (bid >> 3);
    const int bx = swz / gy, by = swz % gy;
    const int m0 = by * 256, n0 = bx * 256;

    const int r0 = tid >> 2, sq = tid & 3;
    const int sd = sq ^ ((r0 >> 1) & 3);
    const bf16_t* At = A  + (size_t)(m0 + r0) * K + sd * 8;
    const bf16_t* Bt = Bm + (size_t)(n0 + r0) * K + sd * 8;
    const size_t rs128 = (size_t)128 * K;

    const int axor = ((c >> 1) & 3) << 4;
    const int gb   = (g << 4) ^ axor;
    const int aRow = (wr * 128 + c) * 64 + gb;
    const int bRow = 32768 + (wc * 64 + c) * 64 + gb;

    f32x4 acc[8][4];
#pragma unroll
    for (int i = 0; i < 8; i++)
#pragma unroll
        for (int j = 0; j < 4; j++) acc[i][j] = (f32x4){0.f, 0.f, 0.f, 0.f};

    auto stA = [&](int kt, int kh, int db) {
        const bf16_t* s = At + (size_t)kt * 64 + kh * 32;
        char* d = smem + db * 65536 + kh * 16384 + tid * 16;
        async16(s, (bf16_t*)d);
        async16(s + rs128, (bf16_t*)(d + 8192));
    };
    auto stB = [&](int kt, int kh, int db) {
        const bf16_t* s = Bt + (size_t)kt * 64 + kh * 32;
        char* d = smem + db * 65536 + 32768 + kh * 16384 + tid * 16;
        async16(s, (bf16_t*)d);
        async16(s + rs128, (bf16_t*)(d + 8192));
    };

    const int nkt = K >> 6;
    stA(0, 0, 0); stB(0, 0, 0); stA(0, 1, 0); stB(0, 1, 0);
    stA(1, 0, 1); stB(1, 0, 1);
    asm volatile("s_waitcnt vmcnt(4)" ::: "memory");
    __builtin_amdgcn_s_barrier();
    asm volatile("" ::: "memory");

    auto tile = [&](int t, int db) {
        const int kt1 = (t + 1 < nkt) ? t + 1 : 0;
        const int kt2 = (t + 2 < nkt) ? t + 2 : 0;
        const char* base = smem + db * 65536;
        bf16x8 Bf[4], Af[4];
#pragma unroll
        for (int ph = 0; ph < 4; ph++) {
            const int ks = ph >> 1, mh = ph & 1;
            if (mh == 0) {
#pragma unroll
                for (int ni = 0; ni < 4; ni++)
                    Bf[ni] = *(const bf16x8*)(base + ks * 16384 + ni * 1024 + bRow);
            }
#pragma unroll
            for (int r4 = 0; r4 < 4; r4++)
                Af[r4] = *(const bf16x8*)(base + ks * 16384 + (mh * 4 + r4) * 1024 + aRow);
            if (ph == 0)      stA(kt1, 1, db ^ 1);
            else if (ph == 1) { stB(kt1, 1, db ^ 1);
                                asm volatile("s_waitcnt vmcnt(4)" ::: "memory"); }
            else if (ph == 2) stA(kt2, 0, db);
            else              stB(kt2, 0, db);
            asm volatile("" ::: "memory");
            __builtin_amdgcn_s_barrier();
            asm volatile("" ::: "memory");
            __builtin_amdgcn_s_setprio(1);
#pragma unroll
            for (int r4 = 0; r4 < 4; r4++)
#pragma unroll
                for (int ni = 0; ni < 4; ni++)
                    acc[mh * 4 + r4][ni] = mfma16(Af[r4], Bf[ni], acc[mh * 4 + r4][ni]);
            __builtin_amdgcn_s_setprio(0);
            asm volatile("" ::: "memory");
            __builtin_amdgcn_s_barrier();
            asm volatile("" ::: "memory");
        }
    };

#pragma unroll 1
    for (int t = 0; t < nkt; t += 2) { tile(t, 0); tile(t + 1, 1); }

    asm volatile("s_waitcnt vmcnt(0)" ::: "memory");

    float bi[4];
#pragma unroll
    for (int ni = 0; ni < 4; ni++) bi[ni] = bias[n0 + wc * 64 + ni * 16 + c];
    if (MODE == 1) {
        bf16_t* C = (bf16_t*)Cout;
        const int grp = (n0 >> 6) + wc;
#pragma unroll
        for (int mi = 0; mi < 8; mi++) {
#pragma unroll
            for (int i = 0; i < 4; i++) {
                int m = m0 + wr * 128 + mi * 16 + g * 4 + i;
                bf16_t* crow = C + (size_t)m * N + n0 + wc * 64 + c;
                float s = 0.f;
#pragma unroll
                for (int ni = 0; ni < 4; ni++) {
                    float v = acc[mi][ni][i] + bi[ni];
                    crow[ni * 16] = (bf16_t)v;
                    s += v * v;
                }
#pragma unroll
                for (int msk = 1; msk < 16; msk <<= 1) s += __shfl_xor(s, msk);
                if (c == 0) Psum[(size_t)m * 96 + grp] = s;
            }
        }
    } else {
        float* C = (float*)Cout;
#pragma unroll
        for (int mi = 0; mi < 8; mi++) {
#pragma unroll
            for (int i = 0; i < 4; i++) {
                int m = m0 + wr * 128 + mi * 16 + g * 4 + i;
                float* crow = C + (size_t)m * N + n0 + wc * 64 + c;
#pragma unroll
                for (int ni = 0; ni < 4; ni++) crow[ni * 16] = acc[mi][ni][i] + bi[ni];
            }
        }
    }
}

// ---------------- in-place RMSNorm + RoPE on bf16 QKV rows ----------------
__global__ __launch_bounds__(256) void rmsrope2_kernel(bf16_t* __restrict__ QKV,
                                                       const float* __restrict__ Psum,
                                                       const float* __restrict__ gq,
                                                       const float* __restrict__ gk,
                                                       const float* __restrict__ rot,
                                                       float qscale) {
    const int t = blockIdx.x;
    const int s = t % NS;
    const int tid = threadIdx.x;
    __shared__ float sh[2];
    float p = 0.f;
    if (tid < 64) p = Psum[(size_t)t * 96 + tid];
#pragma unroll
    for (int msk = 1; msk < 32; msk <<= 1) p += __shfl_xor(p, msk);
    if (tid == 0) sh[0] = p;
    if (tid == 32) sh[1] = p;
    __syncthreads();
    const float sclQ = rsqrtf(sh[0] * (1.f / (float)ND) + 1e-6f);
    const float sclK = rsqrtf(sh[1] * (1.f / (float)ND) + 1e-6f);

    const int col = tid * 8, hd = col & (NHD - 1);
    const float* rr = rot + (size_t)s * (2 * NHD);
    float cc[4], sn[4];
#pragma unroll
    for (int u = 0; u < 4; u++) {
        cc[u] = rr[hd + 2 * u];
        sn[u] = rr[NHD + hd + 2 * u + 1];
    }
    bf16_t* row = QKV + (size_t)t * N3;

    bf16x8 xq = *(bf16x8*)(row + col);
    bf16x8 xk = *(bf16x8*)(row + ND + col);
    bf16x8 oq, ok;
#pragma unroll
    for (int u = 0; u < 4; u++) {
        float e  = (float)xq[2 * u]     * sclQ * gq[col + 2 * u];
        float od = (float)xq[2 * u + 1] * sclQ * gq[col + 2 * u + 1];
        oq[2 * u]     = (bf16_t)((e * cc[u] - od * sn[u]) * qscale);
        oq[2 * u + 1] = (bf16_t)((e * sn[u] + od * cc[u]) * qscale);
        float ek  = (float)xk[2 * u]     * sclK * gk[col + 2 * u];
        float odk = (float)xk[2 * u + 1] * sclK * gk[col + 2 * u + 1];
        ok[2 * u]     = (bf16_t)(ek * cc[u] - odk * sn[u]);
        ok[2 * u + 1] = (bf16_t)(ek * sn[u] + odk * cc[u]);
    }
    *(bf16x8*)(row + col) = oq;
    *(bf16x8*)(row + ND + col) = ok;
}

// ---------------- V transpose: QKV bf16 V-cols -> [bh][d][s] ----------------
__global__ __launch_bounds__(256) void vtrans_kernel(const bf16_t* __restrict__ QKV,
                                                     bf16_t* __restrict__ VTg) {
    __shared__ bf16_t T[128 * 65];
    const int tid = threadIdx.x;
    const int st = blockIdx.x;                // s-tile of 64
    const int bh = blockIdx.y;
    const int b = bh >> 4, h = bh & 15;
    const int ds = tid >> 4, ssx = tid & 15;
#pragma unroll
    for (int i = 0; i < 4; i++) {
        int sl = ssx + i * 16;
        const bf16_t* xr = QKV + (size_t)(b * NS + st * 64 + sl) * N3 + 2 * ND + h * NHD;
        bf16x8 v = *(const bf16x8*)(xr + ds * 8);
#pragma unroll
        for (int u = 0; u < 8; u++) T[(ds * 8 + u) * 65 + sl] = v[u];
    }
    __syncthreads();
#pragma unroll
    for (int q = 0; q < 4; q++) {
        int chunk = q * 256 + tid;
        int d = chunk >> 3, sc8 = chunk & 7;
        bf16x8 o;
#pragma unroll
        for (int u = 0; u < 8; u++) o[u] = T[d * 65 + sc8 * 8 + u];
        *(bf16x8*)(VTg + ((size_t)bh * NHD + d) * NS + st * 64 + sc8 * 8) = o;
    }
}

// ---------------- flash attention (R5 structure, byte-exact revert) ---------
// S^T trick, fixed-max softmax, balanced key chunks, 64-key iters, register
// prefetch depth 1, single per-wave Ps.  Q/K read from fused QKV rows
// (stride 6144 elems; per-(token,head) 128-elem chunks are contiguous).
__global__ __launch_bounds__(256, 3) void attn_kernel(const bf16_t* __restrict__ QKV,
                                                      const bf16_t* __restrict__ Vg,
                                                      bf16_t* __restrict__ Og,
                                                      float* __restrict__ PartA,
                                                      float* __restrict__ PartB,
                                                      float* __restrict__ PartL) {
    __shared__ bf16_t Ks[64 * 136];       // [key][d], stride 136 (17408 B)
    __shared__ bf16_t Vs[128 * 72];       // [d][key], stride 72  (18432 B)
    __shared__ bf16_t Ps[4][16 * 72];     // per-wave P, [q][key], stride 72 (9216 B)
    const int tid = threadIdx.x;
    const int wid = tid >> 6, lane = tid & 63;
    const int g = lane >> 4, c = lane & 15;
    const int x = blockIdx.x, bh = blockIdx.y;
    const int b = bh >> 4, h = bh & 15;
    const float FM = 18.0f;

    int qb, k0, niter, tile;
    bool direct;
    if (x < 8) { qb = x; k0 = 0; niter = 16; direct = true; tile = 0; }
    else {
        int t = x - 8;
        qb = 8 + (t >> 1);
        int ch = t & 1;
        k0 = ch * 1536; niter = 24; direct = false;
        tile = (bh * 16 + (qb - 8)) * 2 + ch;      // 0..1023
    }
    const int q0 = qb * 128 + wid * 32;

    // Q B-fragments for 2 q-subtiles, held in registers for the whole kernel
    bf16x8 qf[2][4];
#pragma unroll
    for (int f = 0; f < 2; f++) {
        const bf16_t* qrow = QKV + (size_t)(b * NS + q0 + f * 16 + c) * N3 + h * NHD;
#pragma unroll
        for (int d = 0; d < 4; d++) qf[f][d] = *(const bf16x8*)(qrow + d * 32 + g * 8);
    }

    f32x4 o[2][8];
#pragma unroll
    for (int f = 0; f < 2; f++)
#pragma unroll
        for (int nt = 0; nt < 8; nt++) o[f][nt] = (f32x4){0.f, 0.f, 0.f, 0.f};
    float l[2] = {0.f, 0.f};

    // staging assignments (64-key tiles)
    const int skrow = tid >> 2, skc = tid & 3;    // K: 64 rows x 4 chunks of 8 elem
    const int svd = tid >> 1, svc = tid & 1;      // V: 128 rows x 2 chunks of 8 keys
    const bf16_t* kbase = QKV + (size_t)(b * NS + skrow) * N3 + ND + h * NHD;
    const bf16_t* vbase = Vg + ((size_t)bh * NHD + svd) * NS;
    bf16_t* pw = &Ps[wid][0];

    u32x4 kreg[4], vreg[4];
    {   // preload iteration 0
        const u32x4* ks = (const u32x4*)(kbase + (size_t)k0 * N3);
        const u32x4* vs = (const u32x4*)(vbase + k0);
#pragma unroll
        for (int j = 0; j < 4; j++) { kreg[j] = ks[skc + 4 * j]; vreg[j] = vs[svc + 2 * j]; }
    }

    for (int it = 0; it < niter; it++) {
        __syncthreads();    // previous iteration's LDS readers done
#pragma unroll
        for (int j = 0; j < 4; j++) {
            *(u32x4*)&Ks[skrow * 136 + (skc + 4 * j) * 8] = kreg[j];
            *(u32x4*)&Vs[svd * 72 + (svc + 2 * j) * 8]    = vreg[j];
        }
        __syncthreads();
        if (it + 1 < niter) {       // prefetch next tile; latency overlaps compute
            const int kb = k0 + (it + 1) * 64;
            const u32x4* ks = (const u32x4*)(kbase + (size_t)kb * N3);
            const u32x4* vs = (const u32x4*)(vbase + kb);
#pragma unroll
            for (int j = 0; j < 4; j++) { kreg[j] = ks[skc + 4 * j]; vreg[j] = vs[svc + 2 * j]; }
        }

        // S^T = mfma(K-frag, Q-frag): S[q=q0+f*16+c][key = kt*16 + g*4 + i]
        f32x4 sv[2][4];
#pragma unroll
        for (int f = 0; f < 2; f++)
#pragma unroll
            for (int kt = 0; kt < 4; kt++) sv[f][kt] = (f32x4){0.f, 0.f, 0.f, 0.f};
#pragma unroll
        for (int kt = 0; kt < 4; kt++)
#pragma unroll
            for (int dd = 0; dd < 4; dd++) {
                bf16x8 kf = *(const bf16x8*)&Ks[(kt * 16 + c) * 136 + dd * 32 + g * 8];
#pragma unroll
                for (int f = 0; f < 2; f++) sv[f][kt] = mfma16(kf, qf[f][dd], sv[f][kt]);
            }

        // fixed-max softmax p = exp2(s-FM); l per-lane (deferred reduction).
        bf16x8 pf[2][2];
#pragma unroll
        for (int f = 0; f < 2; f++) {
#pragma unroll
            for (int kt = 0; kt < 4; kt++) {
                bf16x4 pk;
#pragma unroll
                for (int i = 0; i < 4; i++) {
                    float pv = exp2f(sv[f][kt][i] - FM);
                    l[f] += pv;
                    pk[i] = (bf16_t)pv;
                }
                *(bf16x4*)&pw[c * 72 + kt * 16 + g * 4] = pk;
            }
#pragma unroll
            for (int s = 0; s < 2; s++)
                pf[f][s] = *(const bf16x8*)&pw[c * 72 + s * 32 + g * 8];
        }

        // O^T += mfma(V^T-frag, P-frag), contraction over 64 keys
#pragma unroll
        for (int s = 0; s < 2; s++)
#pragma unroll
            for (int nt = 0; nt < 8; nt++) {
                bf16x8 vf = *(const bf16x8*)&Vs[(nt * 16 + c) * 72 + s * 32 + g * 8];
                o[0][nt] = mfma16(vf, pf[0][s], o[0][nt]);
                o[1][nt] = mfma16(vf, pf[1][s], o[1][nt]);
            }
    }

    if (direct) {
        // reduce l over g-groups, normalize, store bf16 [b][s][h][d]
#pragma unroll
        for (int f = 0; f < 2; f++) {
            float lt = l[f];
            lt += __shfl_xor(lt, 16);
            lt += __shfl_xor(lt, 32);
            float inv = 1.0f / lt;
            bf16_t* orow = Og + (((size_t)b * NS + q0 + f * 16 + c) * NH + h) * NHD;
#pragma unroll
            for (int nt = 0; nt < 8; nt++) {
                bf16x4 ov;
#pragma unroll
                for (int i = 0; i < 4; i++) ov[i] = (bf16_t)(o[f][nt][i] * inv);
                *(bf16x4*)(orow + nt * 16 + g * 4) = ov;
            }
        }
    } else {
        // write unnormalized f32 partial tile [q 0..127][d 0..127] + l partials
        float* pt = (tile < 768) ? (PartA + (size_t)tile * 16384)
                                 : (PartB + (size_t)(tile - 768) * 16384);
#pragma unroll
        for (int f = 0; f < 2; f++) {
            float lt = l[f];
            lt += __shfl_xor(lt, 16);
            lt += __shfl_xor(lt, 32);
            if (g == 0) PartL[(size_t)tile * 128 + wid * 32 + f * 16 + c] = lt;
            float* prow = pt + (wid * 32 + f * 16 + c) * 128;
#pragma unroll
            for (int nt = 0; nt < 8; nt++)
                *(f32x4*)(prow + nt * 16 + g * 4) = o[f][nt];
        }
    }
}

// ---------------- combine: sum 2 chunk partials, normalize, write bf16 Ob ----
__global__ __launch_bounds__(256) void combine_kernel(const float* __restrict__ PartA,
                                                      const float* __restrict__ PartB,
                                                      const float* __restrict__ PartL,
                                                      bf16_t* __restrict__ Og) {
    const int qc = blockIdx.x, bh = blockIdx.y;
    const int b = bh >> 4, h = bh & 15;
    const int t0 = (bh * 16 + qc) * 2;            // even; pair never straddles 768
    const float* p0 = (t0 < 768) ? (PartA + (size_t)t0 * 16384)
                                 : (PartB + (size_t)(t0 - 768) * 16384);
    const float* p1 = (t0 + 1 < 768) ? (PartA + (size_t)(t0 + 1) * 16384)
                                     : (PartB + (size_t)(t0 + 1 - 768) * 16384);
    __shared__ float invl[128];
    const int tid = threadIdx.x;
    if (tid < 128)
        invl[tid] = 1.0f / (PartL[(size_t)t0 * 128 + tid] + PartL[(size_t)(t0 + 1) * 128 + tid]);
    __syncthreads();
    const int qb = 8 + qc;
#pragma unroll
    for (int j = 0; j < 16; j++) {
        int idx = j * 1024 + tid * 4;             // flat f32 index in 128x128 tile
        int q = idx >> 7, d = idx & 127;
        f32x4 a = *(const f32x4*)(p0 + idx);
        f32x4 c4 = *(const f32x4*)(p1 + idx);
        float inv = invl[q];
        bf16x4 ov;
#pragma unroll
        for (int i = 0; i < 4; i++) ov[i] = (bf16_t)((a[i] + c4[i]) * inv);
        *(bf16x4*)(Og + (((size_t)b * NS + qb * 128 + q) * NH + h) * NHD + d) = ov;
    }
}

// ---------------------------------------------------------------------------
extern "C" void kernel_launch(void* const* d_in, const int* in_sizes, int n_in,
                              void* d_out, int out_size, void* d_ws, size_t ws_size,
                              hipStream_t stream) {
    const float* hs  = (const float*)d_in[0];
    const float* rot = (const float*)d_in[1];
    const float* Wq  = (const float*)d_in[2];
    const float* bq  = (const float*)d_in[3];
    const float* Wk  = (const float*)d_in[4];
    const float* bk  = (const float*)d_in[5];
    const float* Wv  = (const float*)d_in[6];
    const float* bv  = (const float*)d_in[7];
    const float* gq  = (const float*)d_in[8];
    const float* gk  = (const float*)d_in[9];
    const float* Wo  = (const float*)d_in[10];
    const float* bo  = (const float*)d_in[11];
    float* out = (float*)d_out;

    // ws map (high-water 146800640 B):
    //   0        .. 25165824  Xb (hs bf16)            [dead after QKV GEMM; Ob]
    //   25165824 .. 50331648  Wqkv bf16               [dead after QKV GEMM]
    //   50331648 .. 58720256  Wo bf16                 [live until final GEMM]
    //   58720256 ..134217728  QKVb bf16 [6144][6144]
    //  134217728 ..146800640  VTb [bh][d][s]
    // Attention-time reuse:
    //   Ob    = ws[0..12.6MB)       (Xb region)
    //   PartB = ws[25165824..42MB)  (Wqkv region, 256 tiles)
    //   PartL = ws[41943040..42.5MB)
    //   PartA = d_out (768 tiles x 65536 B = 50331648 exactly)
    char* ws = (char*)d_ws;
    bf16_t* Xb    = (bf16_t*)(ws + 0);
    bf16_t* Wqkvb = (bf16_t*)(ws + 25165824);
    bf16_t* Wob   = (bf16_t*)(ws + 50331648);
    bf16_t* QKVb  = (bf16_t*)(ws + 58720256);
    bf16_t* VTb   = (bf16_t*)(ws + 134217728);
    bf16_t* Ob    = (bf16_t*)(ws + 0);
    float*  PartB = (float*)(ws + 25165824);
    float*  PartL = (float*)(ws + 41943040);
    float*  Psum  = out;                          // 6144*96*4 = 2359296 B
    float*  bqkv  = (float*)((char*)d_out + 3145728);
    float*  PartA = out;

    const float QSCALE = 1.4426950408889634f * 0.08838834764831845f; // log2(e)/sqrt(128)

    // 1. casts + bias concat
    cast_bf16_kernel<<<12288, 256, 0, stream>>>(hs, Xb, NTOK * ND / 4);
    cast_bf16_kernel<<<4096, 256, 0, stream>>>(Wq, Wqkvb, ND * ND / 4);
    cast_bf16_kernel<<<4096, 256, 0, stream>>>(Wk, Wqkvb + (size_t)ND * ND, ND * ND / 4);
    cast_bf16_kernel<<<4096, 256, 0, stream>>>(Wv, Wqkvb + (size_t)2 * ND * ND, ND * ND / 4);
    cast_bf16_kernel<<<4096, 256, 0, stream>>>(Wo, Wob, ND * ND / 4);
    bias_concat_kernel<<<24, 256, 0, stream>>>(bq, bk, bv, bqkv);

    // 2. fused QKV projection: 256^2 counted-vmcnt GEMM (576 blocks)
    gemm256<1><<<dim3(N3 / 256, NTOK / 256), 512, 0, stream>>>(Xb, Wqkvb, bqkv,
                                                               (void*)QKVb, Psum,
                                                               N3, ND);
    // 3. in-place RMSNorm + RoPE on Q,K segments
    rmsrope2_kernel<<<NTOK, 256, 0, stream>>>(QKVb, Psum, gq, gk, rot, QSCALE);
    // 4. V transpose
    vtrans_kernel<<<dim3(48, 32), 256, 0, stream>>>(QKVb, VTb);
    // 5. attention (balanced chunks, 64-key iters, prefetch) + combine
    attn_kernel<<<dim3(40, 32), 256, 0, stream>>>(QKVb, VTb, Ob, PartA, PartB, PartL);
    combine_kernel<<<dim3(16, 32), 256, 0, stream>>>(PartA, PartB, PartL, Ob);
    // 6. output projection: 256^2 template (192 blocks)
    gemm256<0><<<dim3(ND / 256, NTOK / 256), 512, 0, stream>>>(Ob, Wob, bo,
                                                               (void*)out, nullptr,
                                                               ND, ND);
}